// Round 1
// 499.249 us; speedup vs baseline: 1.0462x; 1.0462x over previous
//
#include <hip/hip_runtime.h>
#include <hip/hip_bf16.h>
#include <math.h>

#define NNODES 100000
#define NBMAX 512          // bucket arrays sized to 512; actual nb = ceil(N/256) = 391
#define CH 8192            // edges per partition block

typedef __hip_bfloat16 bf16;
typedef __attribute__((ext_vector_type(8))) short short8;   // bf16x8 MFMA A/B frag
typedef __attribute__((ext_vector_type(4))) float f32x4;    // MFMA C/D frag
typedef __attribute__((ext_vector_type(2))) float f32x2;

__device__ inline unsigned pack_bf16x2(float a, float b) {
    __hip_bfloat162 p;
    p.x = __float2bfloat16(a);
    p.y = __float2bfloat16(b);
    return *(unsigned*)&p;
}

__device__ inline float2 unpack_bf16x2(unsigned u) {
    __hip_bfloat162 p = *(__hip_bfloat162*)&u;
    return make_float2(__bfloat162float(p.x), __bfloat162float(p.y));
}

__device__ inline unsigned char f32_to_fp8(float v) {
    int p = __builtin_amdgcn_cvt_pk_fp8_f32(v, v, 0, false);   // OCP e4m3 on gfx950
    return (unsigned char)(p & 0xff);
}

// ---------------- phase A: bucket histogram (bucket = dst >> 8) ----------------
__global__ __launch_bounds__(256) void bucket_hist(const int* __restrict__ dst,
                                                   int* __restrict__ bcount, int E, int nb) {
    __shared__ int hist[NBMAX];
    int t = threadIdx.x;
    for (int i = t; i < NBMAX; i += 256) hist[i] = 0;
    __syncthreads();
    int e0 = blockIdx.x * CH;
#pragma unroll
    for (int k = 0; k < 32; ++k) {
        int e = e0 + t + k * 256;
        if (e < E) atomicAdd(&hist[dst[e] >> 8], 1);
    }
    __syncthreads();
    for (int i = t; i < nb; i += 256)
        if (hist[i]) atomicAdd(&bcount[i], hist[i]);
}

// ---------------- phase B: scan bucket counts (1 block, 512 threads) ----------------
__global__ __launch_bounds__(512) void bucket_scan(const int* __restrict__ bcount,
                                                   int* __restrict__ boff,
                                                   int* __restrict__ bcursor,
                                                   int* __restrict__ off, int nb, int n) {
    __shared__ int wsum[8];
    int t = threadIdx.x;
    int v = (t < nb) ? bcount[t] : 0;
    int lane = t & 63, wv = t >> 6;
    int incl = v;
#pragma unroll
    for (int d = 1; d < 64; d <<= 1) {
        int x = __shfl_up(incl, d, 64);
        if (lane >= d) incl += x;
    }
    if (lane == 63) wsum[wv] = incl;
    __syncthreads();
    int wo = 0;
    for (int k = 0; k < wv; ++k) wo += wsum[k];
    int excl = wo + incl - v;
    if (t <= nb) {
        boff[t] = excl;
        if (t < nb) bcursor[t] = excl;
    }
    if (t == nb) off[n] = excl;      // grand total == E
}

// ---------------- phase C: partition edges into bucket-contiguous ranges ----------------
__global__ __launch_bounds__(256) void partition(const int* __restrict__ src,
                                                 const int* __restrict__ dst,
                                                 int* __restrict__ bcursor,
                                                 int2* __restrict__ part, int E, int nb) {
    __shared__ int hist[NBMAX];
    __shared__ int lstart[NBMAX];
    __shared__ int gbase[NBMAX];
    __shared__ int cursor[NBMAX];
    __shared__ int2 sorted[CH];
    int t = threadIdx.x;
    int e0 = blockIdx.x * CH;
    for (int i = t; i < NBMAX; i += 256) hist[i] = 0;
    __syncthreads();
    int mys[32], myd[32];
#pragma unroll
    for (int k = 0; k < 32; ++k) {
        int e = e0 + t + k * 256;
        int s = 0, d = -1;
        if (e < E) { s = src[e]; d = dst[e]; }
        mys[k] = s; myd[k] = d;
        if (d >= 0) atomicAdd(&hist[d >> 8], 1);
    }
    __syncthreads();
    if (t < 64) {
        int base = t * 8;
        int tmp[8];
        int sum = 0;
#pragma unroll
        for (int j = 0; j < 8; ++j) { tmp[j] = hist[base + j]; sum += tmp[j]; }
        int incl = sum;
#pragma unroll
        for (int d = 1; d < 64; d <<= 1) {
            int x = __shfl_up(incl, d, 64);
            if (t >= d) incl += x;
        }
        int excl = incl - sum;
#pragma unroll
        for (int j = 0; j < 8; ++j) {
            lstart[base + j] = excl;
            cursor[base + j] = excl;
            excl += tmp[j];
        }
    }
    __syncthreads();
    for (int i = t; i < nb; i += 256) {
        int c = hist[i];
        gbase[i] = c ? atomicAdd(&bcursor[i], c) : 0;
    }
    __syncthreads();
#pragma unroll
    for (int k = 0; k < 32; ++k) {
        int d = myd[k];
        if (d >= 0) {
            int lpos = atomicAdd(&cursor[d >> 8], 1);
            sorted[lpos] = make_int2(mys[k], d);
        }
    }
    __syncthreads();
    int cnt = min(CH, E - e0);
    for (int i = t; i < cnt; i += 256) {
        int2 rec = sorted[i];
        int b = rec.y >> 8;
        part[gbase[b] + (i - lstart[b])] = rec;
    }
}

// ---------------- phase D+E fused: degrees -> off[]/dinv[], then CSR fill --------------
// Second pass over part[] hits L2 (per-block range is ~64 KB and was just read).
__global__ __launch_bounds__(256) void nodes_fill(const int2* __restrict__ part,
                                                  const int* __restrict__ boff,
                                                  float* __restrict__ dinv,
                                                  int* __restrict__ off,
                                                  int* __restrict__ edges, int n) {
    __shared__ int ndeg[256];
    __shared__ int ws2[4];
    __shared__ int offl[256];
    int b = blockIdx.x;
    int t = threadIdx.x;
    ndeg[t] = 0;
    __syncthreads();
    int r0 = boff[b], r1 = boff[b + 1];
    for (int i = r0 + t; i < r1; i += 256)
        atomicAdd(&ndeg[part[i].y & 255], 1);
    __syncthreads();
    int deg = ndeg[t];
    int node = b * 256 + t;
    int lane = t & 63, wv = t >> 6;
    int incl = deg;
#pragma unroll
    for (int d = 1; d < 64; d <<= 1) {
        int x = __shfl_up(incl, d, 64);
        if (lane >= d) incl += x;
    }
    if (lane == 63) ws2[wv] = incl;
    __syncthreads();
    int wo = 0;
    for (int k = 0; k < wv; ++k) wo += ws2[k];
    int node_off = r0 + wo + incl - deg;
    if (node < n) {
        off[node] = node_off;
        dinv[node] = rsqrtf((float)(deg + 1));     // +1: self-loop
    }
    offl[t] = node_off;
    ndeg[t] = 0;                                   // reuse as fill cursor
    __syncthreads();
    for (int i = r0 + t; i < r1; i += 256) {
        int2 rec = part[i];
        int dloc = rec.y & 255;
        int lpos = atomicAdd(&ndeg[dloc], 1);
        edges[offl[dloc] + lpos] = rec.x;
    }
}

// ---------------- weight prep: WT[n][k] = bf16(W[k][n]) ----------------
__global__ void prep_w(const float* __restrict__ W, bf16* __restrict__ WT, int K, int Nout) {
    int idx = blockIdx.x * blockDim.x + threadIdx.x;
    if (idx >= K * Nout) return;
    int nn = idx / K;
    int kk = idx - nn * K;
    WT[idx] = __float2bfloat16(W[kk * Nout + nn]);
}

#define WSTRIDE 136   // bf16 elements; 272 B = 17x16 B (aligned), 2-way LDS conflict only

// ---------------- MFMA GEMM (LDS-staged WT), A fp32 [n,128] -> fp8 h' = h*dinv[row] ----
__global__ __launch_bounds__(256) void gemm128_f32A(const float* __restrict__ A,
                                                    const bf16* __restrict__ WT,
                                                    const float* __restrict__ dinv,
                                                    unsigned char* __restrict__ C, int n) {
    __shared__ bf16 wl[128 * WSTRIDE];   // 34 KB
    int t = threadIdx.x;
#pragma unroll
    for (int l = 0; l < 8; ++l) {
        int chunk = t + l * 256;           // 0..2047, 16B chunks
        int row = chunk >> 4, ch = chunk & 15;
        *(uint4*)&wl[row * WSTRIDE + ch * 8] = *(const uint4*)&WT[row * 128 + ch * 8];
    }
    __syncthreads();
    int wave = t >> 6, lane = t & 63;
    int m = lane & 15, q = lane >> 4;
    int row_base = blockIdx.x * 128 + wave * 32;
    int r0 = min(row_base + m, n - 1);
    int r1 = min(row_base + 16 + m, n - 1);

    f32x4 acc[2][8];
#pragma unroll
    for (int g = 0; g < 2; ++g)
#pragma unroll
        for (int c = 0; c < 8; ++c) acc[g][c] = (f32x4)(0.f);

#pragma unroll
    for (int kt = 0; kt < 4; ++kt) {
        short8 af[2];
#pragma unroll
        for (int g = 0; g < 2; ++g) {
            const float* ap = &A[(size_t)(g ? r1 : r0) * 128 + kt * 32 + q * 8];
            float4 f0 = *(const float4*)ap;
            float4 f1 = *(const float4*)(ap + 4);
            union { uint4 u; short8 s; } cv;
            cv.u.x = pack_bf16x2(f0.x, f0.y);
            cv.u.y = pack_bf16x2(f0.z, f0.w);
            cv.u.z = pack_bf16x2(f1.x, f1.y);
            cv.u.w = pack_bf16x2(f1.z, f1.w);
            af[g] = cv.s;
        }
#pragma unroll
        for (int c = 0; c < 8; ++c) {
            short8 bf = *(const short8*)&wl[(c * 16 + m) * WSTRIDE + kt * 32 + q * 8];
            acc[0][c] = __builtin_amdgcn_mfma_f32_16x16x32_bf16(af[0], bf, acc[0][c], 0, 0, 0);
            acc[1][c] = __builtin_amdgcn_mfma_f32_16x16x32_bf16(af[1], bf, acc[1][c], 0, 0, 0);
        }
    }
    float dv[2][4];
#pragma unroll
    for (int g = 0; g < 2; ++g)
#pragma unroll
        for (int r = 0; r < 4; ++r) {
            int row = row_base + g * 16 + q * 4 + r;
            dv[g][r] = (row < n) ? dinv[row] : 0.f;
        }
#pragma unroll
    for (int g = 0; g < 2; ++g)
#pragma unroll
        for (int c = 0; c < 8; ++c)
#pragma unroll
            for (int r = 0; r < 4; ++r) {
                int row = row_base + g * 16 + q * 4 + r;
                if (row < n) C[(size_t)row * 128 + c * 16 + m] = f32_to_fp8(acc[g][c][r] * dv[g][r]);
            }
}

// ---------------- MFMA GEMM (LDS-staged WT), A bf16 [n,128] -> fp8 h' ----------------
__global__ __launch_bounds__(256) void gemm128_bf16A(const bf16* __restrict__ A,
                                                     const bf16* __restrict__ WT,
                                                     const float* __restrict__ dinv,
                                                     unsigned char* __restrict__ C, int n) {
    __shared__ bf16 wl[128 * WSTRIDE];   // 34 KB
    int t = threadIdx.x;
#pragma unroll
    for (int l = 0; l < 8; ++l) {
        int chunk = t + l * 256;
        int row = chunk >> 4, ch = chunk & 15;
        *(uint4*)&wl[row * WSTRIDE + ch * 8] = *(const uint4*)&WT[row * 128 + ch * 8];
    }
    __syncthreads();
    int wave = t >> 6, lane = t & 63;
    int m = lane & 15, q = lane >> 4;
    int row_base = blockIdx.x * 128 + wave * 32;
    int r0 = min(row_base + m, n - 1);
    int r1 = min(row_base + 16 + m, n - 1);

    f32x4 acc[2][8];
#pragma unroll
    for (int g = 0; g < 2; ++g)
#pragma unroll
        for (int c = 0; c < 8; ++c) acc[g][c] = (f32x4)(0.f);

#pragma unroll
    for (int kt = 0; kt < 4; ++kt) {
        short8 a0 = *(const short8*)&A[(size_t)r0 * 128 + kt * 32 + q * 8];
        short8 a1 = *(const short8*)&A[(size_t)r1 * 128 + kt * 32 + q * 8];
#pragma unroll
        for (int c = 0; c < 8; ++c) {
            short8 bf = *(const short8*)&wl[(c * 16 + m) * WSTRIDE + kt * 32 + q * 8];
            acc[0][c] = __builtin_amdgcn_mfma_f32_16x16x32_bf16(a0, bf, acc[0][c], 0, 0, 0);
            acc[1][c] = __builtin_amdgcn_mfma_f32_16x16x32_bf16(a1, bf, acc[1][c], 0, 0, 0);
        }
    }
    float dv[2][4];
#pragma unroll
    for (int g = 0; g < 2; ++g)
#pragma unroll
        for (int r = 0; r < 4; ++r) {
            int row = row_base + g * 16 + q * 4 + r;
            dv[g][r] = (row < n) ? dinv[row] : 0.f;
        }
#pragma unroll
    for (int g = 0; g < 2; ++g)
#pragma unroll
        for (int c = 0; c < 8; ++c)
#pragma unroll
            for (int r = 0; r < 4; ++r) {
                int row = row_base + g * 16 + q * 4 + r;
                if (row < n) C[(size_t)row * 128 + c * 16 + m] = f32_to_fp8(acc[g][c][r] * dv[g][r]);
            }
}

// ---------------- MFMA GEMM, A bf16 [n,128] x WT4 [32][128] -> bf16 h'4 = h4*dinv ------
__global__ __launch_bounds__(256) void gemm32_bf16A(const bf16* __restrict__ A,
                                                    const bf16* __restrict__ WT,
                                                    const float* __restrict__ dinv,
                                                    bf16* __restrict__ C, int n) {
    int wave = threadIdx.x >> 6;
    int lane = threadIdx.x & 63;
    int m = lane & 15;
    int q = lane >> 4;
    int row_base = blockIdx.x * 64 + wave * 16;
    int arow = min(row_base + m, n - 1);

    f32x4 acc[2];
    acc[0] = (f32x4)(0.f);
    acc[1] = (f32x4)(0.f);

#pragma unroll
    for (int kt = 0; kt < 4; ++kt) {
        short8 af = *(const short8*)&A[(size_t)arow * 128 + kt * 32 + q * 8];
#pragma unroll
        for (int c = 0; c < 2; ++c) {
            short8 bf = *(const short8*)&WT[(size_t)(c * 16 + m) * 128 + kt * 32 + q * 8];
            acc[c] = __builtin_amdgcn_mfma_f32_16x16x32_bf16(af, bf, acc[c], 0, 0, 0);
        }
    }
    float dv[4];
#pragma unroll
    for (int r = 0; r < 4; ++r) {
        int row = row_base + q * 4 + r;
        dv[r] = (row < n) ? dinv[row] : 0.f;
    }
#pragma unroll
    for (int c = 0; c < 2; ++c)
#pragma unroll
        for (int r = 0; r < 4; ++r) {
            int row = row_base + q * 4 + r;
            if (row < n) C[(size_t)row * 32 + c * 16 + m] = __float2bfloat16(acc[c][r] * dv[r]);
        }
}

// ---------------- aggregation F=128 fp8, dwordx2 gathers, 4 edges/instr ----------------
// Wave per node. lane = (g,d): g = edge slot (0..3), d = 8-byte chunk of the 128 B row.
// One gather instr covers 4 edges x 128 B (16 lanes/row, 8 B/lane).
// Edge indices for a 32-edge chunk batch-prefetched; next chunk's prefetched during
// consume. Sub-32 tail = ONE predicated chunk with OOB slots clamped to zero row h[N].
__global__ __launch_bounds__(256) void agg128(const unsigned char* __restrict__ h,
                                              const int* __restrict__ off,
                                              const int* __restrict__ edges,
                                              const float* __restrict__ dinv,
                                              const float* __restrict__ bias,
                                              bf16* __restrict__ out, int n) {
    int wid = (blockIdx.x * blockDim.x + threadIdx.x) >> 6;
    if (wid >= n) return;
    int lane = threadIdx.x & 63;
    int g = lane >> 4;                 // edge slot within a gather
    int d = lane & 15;                 // 8-byte chunk of row
    const char* hb = (const char*)h;
    unsigned doff = (unsigned)(d << 3);

    f32x2 A0 = {0.f, 0.f}, A1 = {0.f, 0.f}, A2 = {0.f, 0.f}, A3 = {0.f, 0.f};
    {   // self-loop: counted in slot 0 only
        uint2 su = *(const uint2*)(hb + (((unsigned)wid << 7) | doff));
        if (g) { su.x = 0u; su.y = 0u; }
        A0 += __builtin_amdgcn_cvt_pk_f32_fp8((int)su.x, false);
        A1 += __builtin_amdgcn_cvt_pk_f32_fp8((int)su.x, true);
        A2 += __builtin_amdgcn_cvt_pk_f32_fp8((int)su.y, false);
        A3 += __builtin_amdgcn_cvt_pk_f32_fp8((int)su.y, true);
    }

    int i0 = off[wid], i1 = off[wid + 1];
    int i = i0;
    int id[8];
    if (i + 32 <= i1) {
#pragma unroll
        for (int j = 0; j < 8; ++j) id[j] = edges[i + j * 4 + g];
    }
    while (i + 32 <= i1) {             // full 32-edge chunks, unpredicated
        uint2 uu[8];
#pragma unroll
        for (int j = 0; j < 8; ++j)
            uu[j] = *(const uint2*)(hb + (((unsigned)id[j] << 7) | doff));
        int inext = i + 32;
        if (inext + 32 <= i1) {        // prefetch next chunk's indices under consume
#pragma unroll
            for (int j = 0; j < 8; ++j) id[j] = edges[inext + j * 4 + g];
        }
#pragma unroll
        for (int j = 0; j < 8; ++j) {
            A0 += __builtin_amdgcn_cvt_pk_f32_fp8((int)uu[j].x, false);
            A1 += __builtin_amdgcn_cvt_pk_f32_fp8((int)uu[j].x, true);
            A2 += __builtin_amdgcn_cvt_pk_f32_fp8((int)uu[j].y, false);
            A3 += __builtin_amdgcn_cvt_pk_f32_fp8((int)uu[j].y, true);
        }
        i = inext;
    }
    if (i < i1) {                      // tail: one predicated chunk
        int nj = (i1 - i + 3) >> 2;    // 4-edge groups remaining (1..8)
        uint2 uu[8];
#pragma unroll
        for (int j = 0; j < 8; ++j) {
            if (j < nj) {
                int e = i + j * 4 + g;
                int s = edges[e];      // slack-allocated; OOB slots remapped below
                if (e >= i1) s = n;    // zero row
                uu[j] = *(const uint2*)(hb + (((unsigned)s << 7) | doff));
            }
        }
#pragma unroll
        for (int j = 0; j < 8; ++j) {
            if (j < nj) {
                A0 += __builtin_amdgcn_cvt_pk_f32_fp8((int)uu[j].x, false);
                A1 += __builtin_amdgcn_cvt_pk_f32_fp8((int)uu[j].x, true);
                A2 += __builtin_amdgcn_cvt_pk_f32_fp8((int)uu[j].y, false);
                A3 += __builtin_amdgcn_cvt_pk_f32_fp8((int)uu[j].y, true);
            }
        }
    }
    // reduce across the 4 edge slots (slot bits live at lane^16, lane^32)
    float r0 = A0[0], r1 = A0[1], r2 = A1[0], r3 = A1[1];
    float r4 = A2[0], r5 = A2[1], r6 = A3[0], r7 = A3[1];
    r0 += __shfl_xor(r0, 16); r1 += __shfl_xor(r1, 16);
    r2 += __shfl_xor(r2, 16); r3 += __shfl_xor(r3, 16);
    r4 += __shfl_xor(r4, 16); r5 += __shfl_xor(r5, 16);
    r6 += __shfl_xor(r6, 16); r7 += __shfl_xor(r7, 16);
    r0 += __shfl_xor(r0, 32); r1 += __shfl_xor(r1, 32);
    r2 += __shfl_xor(r2, 32); r3 += __shfl_xor(r3, 32);
    r4 += __shfl_xor(r4, 32); r5 += __shfl_xor(r5, 32);
    r6 += __shfl_xor(r6, 32); r7 += __shfl_xor(r7, 32);
    // lane (g,d) owns out dword od = d*4+g = feature pair A_g of chunk d
    float pa = (g & 1) ? r2 : r0;
    float pb = (g & 1) ? r3 : r1;
    float qa = (g & 1) ? r6 : r4;
    float qb = (g & 1) ? r7 : r5;
    pa = (g & 2) ? qa : pa;
    pb = (g & 2) ? qb : pb;

    float dl = dinv[wid];
    int od = d * 4 + g;
    float2 bv = *(const float2*)&bias[od * 2];
    float a0 = fmaxf(pa * dl + bv.x, 0.f);
    float a1 = fmaxf(pb * dl + bv.y, 0.f);
    ((unsigned*)out)[(size_t)wid * 64 + od] = pack_bf16x2(a0, a1);
}

// ---------------- aggregation F=32 bf16, two edges/gather + log_softmax -> fp32 --------
// Row = 64 B = 16 uints. sub = feature pair, pr = edge parity; combine via shfl_xor(16).
__global__ __launch_bounds__(256) void agg32_lsm(const bf16* __restrict__ h,
                                                 const int* __restrict__ off,
                                                 const int* __restrict__ edges,
                                                 const float* __restrict__ dinv,
                                                 const float* __restrict__ bias,
                                                 float* __restrict__ out, int n) {
    int idx = blockIdx.x * blockDim.x + threadIdx.x;
    int node = idx >> 5;
    if (node >= n) return;
    int lane5 = idx & 31;
    int sub = lane5 & 15;      // feature pair: features sub*2, sub*2+1
    int pr = lane5 >> 4;       // edge parity
    const unsigned* h4 = (const unsigned*)h;    // row = 16 uints

    unsigned su = pr ? 0u : h4[(size_t)node * 16 + sub];   // self-loop once
    float2 sf = unpack_bf16x2(su);
    f32x2 acc = {sf.x, sf.y};

    int i0 = off[node], i1 = off[node + 1];
    int i = i0;
    for (; i + 16 <= i1; i += 16) {
        unsigned uu[8];
#pragma unroll
        for (int j = 0; j < 8; ++j) {
            int s = edges[i + j * 2 + pr];
            uu[j] = h4[(size_t)s * 16 + sub];
        }
#pragma unroll
        for (int j = 0; j < 8; ++j) {
            float2 f = unpack_bf16x2(uu[j]);
            acc[0] += f.x; acc[1] += f.y;
        }
    }
    for (; i + 2 <= i1; i += 2) {
        int s = edges[i + pr];
        float2 f = unpack_bf16x2(h4[(size_t)s * 16 + sub]);
        acc[0] += f.x; acc[1] += f.y;
    }
    if (i < i1) {
        unsigned u = pr ? 0u : h4[(size_t)edges[i] * 16 + sub];
        float2 f = unpack_bf16x2(u);
        acc[0] += f.x; acc[1] += f.y;
    }
    // combine parities: lanes l and l^16 hold the same features
    float s0 = acc[0] + __shfl_xor(acc[0], 16);
    float s1 = acc[1] + __shfl_xor(acc[1], 16);

    float dl = dinv[node];
    float2 bv = *(const float2*)&bias[sub * 2];
    float a0 = s0 * dl + bv.x;
    float a1 = s1 * dl + bv.y;
    // log_softmax over 32 features held as pairs in each 16-lane group (duplicated)
    float m = fmaxf(a0, a1);
    for (int d = 8; d; d >>= 1) m = fmaxf(m, __shfl_xor(m, d));
    float e = expf(a0 - m) + expf(a1 - m);
    for (int d = 8; d; d >>= 1) e += __shfl_xor(e, d);
    float lse = m + logf(e);
    if (pr == 0)
        *(float2*)&out[(size_t)node * 32 + sub * 2] = make_float2(a0 - lse, a1 - lse);
}

extern "C" void kernel_launch(void* const* d_in, const int* in_sizes, int n_in,
                              void* d_out, int out_size, void* d_ws, size_t ws_size,
                              hipStream_t stream) {
    const float* x  = (const float*)d_in[0];
    const int*   ei = (const int*)d_in[1];
    const float* W1 = (const float*)d_in[2];
    const float* b1 = (const float*)d_in[3];
    const float* W2 = (const float*)d_in[4];
    const float* b2 = (const float*)d_in[5];
    const float* W3 = (const float*)d_in[6];
    const float* b3 = (const float*)d_in[7];
    const float* W4 = (const float*)d_in[8];
    const float* b4 = (const float*)d_in[9];
    float* out = (float*)d_out;

    const int N = NNODES;
    const int E = in_sizes[1] / 2;
    const int nb = (N + 255) / 256;           // 391 buckets

    char* ws = (char*)d_ws;
    size_t o = 0;
    auto alloc = [&](size_t bytes) -> void* {
        void* p = ws + o;
        o += (bytes + 255) & ~(size_t)255;
        return p;
    };
    int*   bcount  = (int*)alloc((size_t)NBMAX * 4);
    int*   boff    = (int*)alloc((size_t)(NBMAX + 1) * 4);
    int*   bcursor = (int*)alloc((size_t)NBMAX * 4);
    int*   off     = (int*)alloc((size_t)(N + 1) * 4);
    float* dinv    = (float*)alloc((size_t)N * 4);
    int2*  part    = (int2*)alloc((size_t)E * 8);      // aliased as gbuf after build
    int*   edges   = (int*)alloc((size_t)(E + 64) * 4); // +64 slack for tail-chunk reads
    bf16*  wt1     = (bf16*)alloc((size_t)128 * 128 * 2);
    bf16*  wt2     = (bf16*)alloc((size_t)128 * 128 * 2);
    bf16*  wt3     = (bf16*)alloc((size_t)128 * 128 * 2);
    bf16*  wt4     = (bf16*)alloc((size_t)32 * 128 * 2);
    unsigned char* hbuf = (unsigned char*)alloc((size_t)(N + 1) * 128);  // +1: zero row
    bf16*  gbuf    = (bf16*)part;              // part dead after nodes_fill; N*256B == E*8B

    const int* srcv = ei;
    const int* dstv = ei + E;

    hipMemsetAsync(bcount, 0, (size_t)NBMAX * 4, stream);
    hipMemsetAsync(hbuf + (size_t)N * 128, 0, 128, stream);   // fp8 zero row (all layers)

    int pblocks = (E + CH - 1) / CH;
    bucket_hist<<<pblocks, 256, 0, stream>>>(dstv, bcount, E, nb);
    bucket_scan<<<1, 512, 0, stream>>>(bcount, boff, bcursor, off, nb, N);
    partition<<<pblocks, 256, 0, stream>>>(srcv, dstv, bcursor, part, E, nb);
    nodes_fill<<<nb, 256, 0, stream>>>(part, boff, dinv, off, edges, N);

    prep_w<<<64, 256, 0, stream>>>(W1, wt1, 128, 128);
    prep_w<<<64, 256, 0, stream>>>(W2, wt2, 128, 128);
    prep_w<<<64, 256, 0, stream>>>(W3, wt3, 128, 128);
    prep_w<<<16, 256, 0, stream>>>(W4, wt4, 128, 32);

    int gemm128_blocks = (N + 127) / 128;
    int gemm32_blocks = (N + 63) / 64;
    int agg128_blocks = (N + 3) / 4;
    int agg32_blocks = (N * 32 + 255) / 256;

    // Layer 1 (A fp32) -> fp8 h' (pre-scaled by dinv)
    gemm128_f32A<<<gemm128_blocks, 256, 0, stream>>>(x, wt1, dinv, hbuf, N);
    agg128<<<agg128_blocks, 256, 0, stream>>>(hbuf, off, edges, dinv, b1, gbuf, N);
    // Layer 2
    gemm128_bf16A<<<gemm128_blocks, 256, 0, stream>>>(gbuf, wt2, dinv, hbuf, N);
    agg128<<<agg128_blocks, 256, 0, stream>>>(hbuf, off, edges, dinv, b2, gbuf, N);
    // Layer 3
    gemm128_bf16A<<<gemm128_blocks, 256, 0, stream>>>(gbuf, wt3, dinv, hbuf, N);
    agg128<<<agg128_blocks, 256, 0, stream>>>(hbuf, off, edges, dinv, b3, gbuf, N);
    // Layer 4: GEMM to 32 cols (bf16 h'4 - protect final logits), then agg + log_softmax
    gemm32_bf16A<<<gemm32_blocks, 256, 0, stream>>>(gbuf, wt4, dinv, (bf16*)hbuf, N);
    agg32_lsm<<<agg32_blocks, 256, 0, stream>>>((const bf16*)hbuf, off, edges, dinv, b4, out, N);
}